// Round 7
// baseline (739.407 us; speedup 1.0000x reference)
//
#include <hip/hip_runtime.h>

// SelfAttention (non-local block), B=4, C=128, H=W=64, N=HW=4096.
// Outputs: [x + relu(bn(conv(attn@g)))] (2,097,152 f32)  ++  attn (67,108,864 f32)
//
// Layout fact: torch .view(B,-1,C) of a (B,C,H,W) buffer makes the (C,HW)
// conv output buffer literally the (N,C) row-major matrix (n*128+c == o*4096+s).
//
// Round-5 changes vs round-4 (543 us total, ~170 us of which is the harness
// 0xAA re-poison fill — untouchable floor; our kernels ~370 us):
//  - sweep2: P stored f16 in LDS (33.8 KB/block vs 66) -> 4 blocks/CU,
//    16 rows/wave, 1024-block grid -> 16 waves/CU (2x round-4). No barriers.
//  - sweep1: matching 16-rows/wave 1024-block grid.
//  - k_merge_t fused into k_outconv (reads 4 tpart chunks directly).
//  - explicit lgkmcnt(0) fence between LDS flush-reads and next-block writes.
// (Round 7 = second re-run; rounds 5 and 6 both hit GPU-acquisition
// timeouts — no data since round 4.)

typedef _Float16 f16;
typedef __attribute__((ext_vector_type(8))) _Float16 f16x8;
typedef __attribute__((ext_vector_type(4))) float f32x4;

#define CC 128
#define NN 4096
#define BB 4
#define NC (NN * CC)
#define EPS_BN 1e-5f

// workspace offsets (bytes); total 32 MB
#define OFF_THETA (0ull)
#define OFF_PHI   (4ull << 20)
#define OFF_G     (8ull << 20)
#define OFF_GT    (12ull << 20)
#define OFF_PSTAT (8ull << 20)    // aliases G (dead after k_tr_g)
#define OFF_TPART (16ull << 20)   // [4][B][N][C] f16 = 16 MB

// ---------------------------------------------------------------------------
// K1: fused 1x1 conv + bias + relu + BN for theta/phi/g. 1 spatial/thread.
__global__ __launch_bounds__(256) void k_prep(
    const float* __restrict__ x,
    const float* __restrict__ t_w, const float* __restrict__ t_b,
    const float* __restrict__ t_ga, const float* __restrict__ t_be,
    const float* __restrict__ t_me, const float* __restrict__ t_va,
    const float* __restrict__ p_w, const float* __restrict__ p_b,
    const float* __restrict__ p_ga, const float* __restrict__ p_be,
    const float* __restrict__ p_me, const float* __restrict__ p_va,
    const float* __restrict__ g_w, const float* __restrict__ g_b,
    const float* __restrict__ g_ga, const float* __restrict__ g_be,
    const float* __restrict__ g_me, const float* __restrict__ g_va,
    f16* __restrict__ th, f16* __restrict__ ph, f16* __restrict__ gh)
{
  const int s  = blockIdx.x * 256 + threadIdx.x;
  const int o0 = blockIdx.y * 8;
  const int b  = blockIdx.z;
  const float* xb = x + (size_t)b * NC;

  float acc[3][8];
#pragma unroll
  for (int br = 0; br < 3; ++br)
#pragma unroll
    for (int j = 0; j < 8; ++j) acc[br][j] = 0.f;

#pragma unroll 4
  for (int c = 0; c < CC; ++c) {
    float xv = xb[c * NN + s];
#pragma unroll
    for (int j = 0; j < 8; ++j) {
      acc[0][j] += t_w[(o0 + j) * CC + c] * xv;   // uniform -> s_load
      acc[1][j] += p_w[(o0 + j) * CC + c] * xv;
      acc[2][j] += g_w[(o0 + j) * CC + c] * xv;
    }
  }

  f16* outs[3] = { th, ph, gh };
  const float* bi[3] = { t_b,  p_b,  g_b  };
  const float* ga[3] = { t_ga, p_ga, g_ga };
  const float* be[3] = { t_be, p_be, g_be };
  const float* me[3] = { t_me, p_me, g_me };
  const float* va[3] = { t_va, p_va, g_va };
#pragma unroll
  for (int br = 0; br < 3; ++br) {
#pragma unroll
    for (int j = 0; j < 8; ++j) {
      int o = o0 + j;
      float inv = ga[br][o] * rsqrtf(va[br][o] + EPS_BN);
      float add = be[br][o] - me[br][o] * inv;
      float y = fmaxf(acc[br][j] + bi[br][o], 0.f) * inv + add;
      outs[br][(size_t)b * NC + (size_t)o * NN + s] = (f16)y;
    }
  }
}

// ---------------------------------------------------------------------------
// K2: transpose g (N rows, C cols) -> gt (C rows, N cols), fp16.
__global__ __launch_bounds__(256) void k_tr_g(const f16* __restrict__ gh,
                                              f16* __restrict__ gt)
{
  __shared__ f16 tile[64][72];
  const int b   = blockIdx.z;
  const int m0  = blockIdx.x * 64;
  const int c20 = blockIdx.y * 64;
  const f16* gb_ = gh + (size_t)b * NC;
  f16* gtb = gt + (size_t)b * NC;
  const int t = threadIdx.x;
  {
    const int mr = t >> 2, co = (t & 3) * 16;
    f16x8 v0 = *(const f16x8*)(gb_ + (size_t)(m0 + mr) * CC + c20 + co);
    f16x8 v1 = *(const f16x8*)(gb_ + (size_t)(m0 + mr) * CC + c20 + co + 8);
#pragma unroll
    for (int j = 0; j < 8; ++j) tile[co + j][mr] = v0[j];
#pragma unroll
    for (int j = 0; j < 8; ++j) tile[co + 8 + j][mr] = v1[j];
  }
  __syncthreads();
  {
    const int cr = t >> 2, mo = (t & 3) * 16;
    f16x8 w0 = *(const f16x8*)(&tile[cr][mo]);
    f16x8 w1 = *(const f16x8*)(&tile[cr][mo + 8]);
    *(f16x8*)(gtb + (size_t)(c20 + cr) * NN + m0 + mo)     = w0;
    *(f16x8*)(gtb + (size_t)(c20 + cr) * NN + m0 + mo + 8) = w1;
  }
}

// ---------------------------------------------------------------------------
// Sweeps: 4 independent waves/block (no barriers), 16 rows/wave, 1024-col
// chunk. grid 1024 = rb(64) x chunk(4) x b(4); b = bid&3 -> one batch per XCD
// under round-robin dispatch (working set phi+gt+theta ~1 MB << 4 MB L2).
// MFMA 16x16x32 f16 maps: A: l -> A[l&15][(l>>4)*8+e]; B: l -> B[(l>>4)*8+e][l&15];
// D: l,r -> D[(l>>4)*4+r][l&15].
__global__ __launch_bounds__(256, 4) void k_sweep1(
    const f16* __restrict__ th, const f16* __restrict__ ph_,
    float2* __restrict__ pstat)
{
  const int bid = blockIdx.x;
  const int b = bid & 3, chunk = (bid >> 2) & 3, rb = bid >> 4;
  const int tid = threadIdx.x, w = tid >> 6;
  const int lane = tid & 63, lr = lane & 15, lg = lane >> 4;
  const int n0w = rb * 64 + w * 16;
  const f16* tb_ = th  + (size_t)b * NC;
  const f16* pb_ = ph_ + (size_t)b * NC;

  f16x8 a[4];
#pragma unroll
  for (int kk = 0; kk < 4; ++kk)
    a[kk] = *(const f16x8*)(tb_ + (size_t)(n0w + lr) * CC + kk * 32 + lg * 8);

  float m[4], l[4];
#pragma unroll
  for (int r = 0; r < 4; ++r) { m[r] = -1e30f; l[r] = 0.f; }

  const int mbase = chunk * 1024;
#pragma unroll 2
  for (int t = 0; t < 64; ++t) {
    const int mc = mbase + t * 16;
    f16x8 bf[4];
#pragma unroll
    for (int kk = 0; kk < 4; ++kk)
      bf[kk] = *(const f16x8*)(pb_ + (size_t)(mc + lr) * CC + kk * 32 + lg * 8);
    f32x4 d = {0.f, 0.f, 0.f, 0.f};
#pragma unroll
    for (int kk = 0; kk < 4; ++kk)
      d = __builtin_amdgcn_mfma_f32_16x16x32_f16(a[kk], bf[kk], d, 0, 0, 0);
#pragma unroll
    for (int r = 0; r < 4; ++r) {            // defer-max: 1 exp common path
      float dd = d[r] - m[r];
      if (dd > 8.f) { l[r] = l[r] * __expf(-dd) + 1.f; m[r] = d[r]; }
      else          { l[r] += __expf(dd); }
    }
  }
#pragma unroll
  for (int off = 1; off < 16; off <<= 1) {
#pragma unroll
    for (int r = 0; r < 4; ++r) {
      float mo = __shfl_xor(m[r], off);
      float lo = __shfl_xor(l[r], off);
      float mn = fmaxf(m[r], mo);
      l[r] = l[r] * __expf(m[r] - mn) + lo * __expf(mo - mn);
      m[r] = mn;
    }
  }
  if (lr == 0) {
#pragma unroll
    for (int r = 0; r < 4; ++r)
      pstat[(size_t)(chunk * BB + b) * NN + n0w + lg * 4 + r] =
          make_float2(m[r], l[r]);
  }
}

// ---------------------------------------------------------------------------
#define LSTR 132   // f16 row stride in per-wave LDS P-buffer (128 + 4 pad)

__global__ __launch_bounds__(256, 4) void k_sweep2(
    const f16* __restrict__ th, const f16* __restrict__ ph_,
    const f16* __restrict__ gt, const float2* __restrict__ pstat,
    float* __restrict__ attn, f16* __restrict__ tpart)
{
  __shared__ f16 plds[4 * 16 * LSTR];               // 33.8 KB; per-wave private
  const int bid = blockIdx.x;
  const int b = bid & 3, chunk = (bid >> 2) & 3, rb = bid >> 4;
  const int tid = threadIdx.x, w = tid >> 6;
  const int lane = tid & 63, lr = lane & 15, lg = lane >> 4;
  const int n0w = rb * 64 + w * 16;
  const f16* tb_ = th  + (size_t)b * NC;
  const f16* pb_ = ph_ + (size_t)b * NC;
  const f16* gb_ = gt  + (size_t)b * NC;
  f16* pw = plds + w * 16 * LSTR;

  f16x8 aq[4];
#pragma unroll
  for (int kk = 0; kk < 4; ++kk)
    aq[kk] = *(const f16x8*)(tb_ + (size_t)(n0w + lr) * CC + kk * 32 + lg * 8);

  // inline stat merge: S = M + ln(L) for this lane's 4 rows
  float S[4];
#pragma unroll
  for (int r = 0; r < 4; ++r) {
    const int row = n0w + lg * 4 + r;
    float mM = -1e30f, LL = 0.f;
#pragma unroll
    for (int ch = 0; ch < 4; ++ch) {
      float2 ps = pstat[(size_t)(ch * BB + b) * NN + row];
      float mn = fmaxf(mM, ps.x);
      LL = LL * __expf(mM - mn) + ps.y * __expf(ps.x - mn);
      mM = mn;
    }
    S[r] = mM + __logf(LL);
  }

  f32x4 tacc[8];
#pragma unroll
  for (int ct = 0; ct < 8; ++ct) tacc[ct] = (f32x4){0.f, 0.f, 0.f, 0.f};

  float* attn_b = attn + (size_t)b * NN * NN;
  const int mbase = chunk * 1024;
  const int frow = lane >> 4, fcol = (lane & 15) * 8;

  for (int blk = 0; blk < 8; ++blk) {               // 8 x 128-col flush blocks
#pragma unroll
    for (int gi = 0; gi < 4; ++gi) {                // 4 x 32-col groups
      const int m0 = mbase + blk * 128 + gi * 32;
      // ---- QK^T, P = exp(z - S) -> LDS (f16)
#pragma unroll
      for (int sub = 0; sub < 2; ++sub) {
        const int mc = m0 + sub * 16;
        f16x8 bf[4];
#pragma unroll
        for (int kk = 0; kk < 4; ++kk)
          bf[kk] = *(const f16x8*)(pb_ + (size_t)(mc + lr) * CC + kk * 32 + lg * 8);
        f32x4 d = {0.f, 0.f, 0.f, 0.f};
#pragma unroll
        for (int kk = 0; kk < 4; ++kk)
          d = __builtin_amdgcn_mfma_f32_16x16x32_f16(aq[kk], bf[kk], d, 0, 0, 0);
#pragma unroll
        for (int r = 0; r < 4; ++r)
          pw[(lg * 4 + r) * LSTR + gi * 32 + sub * 16 + lr] =
              (f16)__expf(d[r] - S[r]);
      }
      // ---- PV A-fragment straight from LDS (f16, intra-wave ordered)
      f16x8 pa = *(const f16x8*)&pw[lr * LSTR + gi * 32 + lg * 8];
      // ---- PV: tacc[ct] += P(16x32) @ G(32x16c)
#pragma unroll
      for (int ct = 0; ct < 8; ++ct) {
        f16x8 gbf = *(const f16x8*)(gb_ + (size_t)(ct * 16 + lr) * NN + m0 + lg * 8);
        tacc[ct] = __builtin_amdgcn_mfma_f32_16x16x32_f16(pa, gbf, tacc[ct], 0, 0, 0);
      }
    }
    // ---- flush 16 rows x 128 cols: f16 -> f32, 512B contiguous per row, nt
#pragma unroll
    for (int j = 0; j < 4; ++j) {
      const int row = j * 4 + frow;
      f16x8 v = *(const f16x8*)&pw[row * LSTR + fcol];
      f32x4 lo = { (float)v[0], (float)v[1], (float)v[2], (float)v[3] };
      f32x4 hi = { (float)v[4], (float)v[5], (float)v[6], (float)v[7] };
      float* ab = attn_b + (size_t)(n0w + row) * NN + mbase + blk * 128 + fcol;
      __builtin_nontemporal_store(lo, (f32x4*)ab);
      __builtin_nontemporal_store(hi, (f32x4*)(ab + 4));
    }
    // WAR fence: flush reads must complete before next blk's P writes
    asm volatile("s_waitcnt lgkmcnt(0)" ::: "memory");
  }

  // ---- tpart via LDS bounce -> contiguous coalesced f16 stores
#pragma unroll
  for (int ct = 0; ct < 8; ++ct)
#pragma unroll
    for (int r = 0; r < 4; ++r)
      pw[(lg * 4 + r) * LSTR + ct * 16 + lr] = (f16)tacc[ct][r];
  f16* tp = tpart + (size_t)(chunk * BB + b) * NC;
#pragma unroll
  for (int j = 0; j < 4; ++j) {
    const int row = j * 4 + frow;
    f16x8 v = *(const f16x8*)&pw[row * LSTR + fcol];
    *(f16x8*)(tp + (size_t)(n0w + row) * CC + fcol) = v;
  }
}

// ---------------------------------------------------------------------------
// K5: out conv + BN + relu + residual, with tpart 4-chunk merge fused.
// t (N,C) flat == t_fm (C,HW) flat, so t_fm[b][c][hw] = tpart_flat[b][c*NN+hw].
__global__ __launch_bounds__(256) void k_outconv(
    const float* __restrict__ x, const f16* __restrict__ tpart,
    const float* __restrict__ o_w, const float* __restrict__ o_b,
    const float* __restrict__ o_ga, const float* __restrict__ o_be,
    const float* __restrict__ o_me, const float* __restrict__ o_va,
    float* __restrict__ out0)
{
  const int s  = blockIdx.x * 256 + threadIdx.x;
  const int o0 = blockIdx.y * 32;
  const int b  = blockIdx.z;
  const f16* tb_ = tpart + (size_t)b * NC;
  float acc[32];
#pragma unroll
  for (int j = 0; j < 32; ++j) acc[j] = 0.f;

#pragma unroll 2
  for (int c = 0; c < CC; ++c) {
    const size_t idx = (size_t)c * NN + s;
    float tv = (float)tb_[idx] +
               (float)tb_[(size_t)BB * NC + idx] +
               (float)tb_[(size_t)2 * BB * NC + idx] +
               (float)tb_[(size_t)3 * BB * NC + idx];
#pragma unroll
    for (int j = 0; j < 32; ++j)
      acc[j] += o_w[(o0 + j) * CC + c] * tv;        // uniform -> s_load
  }
#pragma unroll
  for (int j = 0; j < 32; ++j) {
    int o = o0 + j;
    float inv = o_ga[o] * rsqrtf(o_va[o] + EPS_BN);
    float add = o_be[o] - o_me[o] * inv;
    float y = fmaxf((acc[j] + o_b[o]) * inv + add, 0.f);
    size_t idx = (size_t)(b * CC + o) * NN + s;
    out0[idx] = x[idx] + y;
  }
}

// ---------------------------------------------------------------------------
extern "C" void kernel_launch(void* const* d_in, const int* in_sizes, int n_in,
                              void* d_out, int out_size, void* d_ws, size_t ws_size,
                              hipStream_t stream)
{
  (void)in_sizes; (void)n_in; (void)out_size; (void)ws_size;
  const float* x    = (const float*)d_in[0];
  const float* t_w  = (const float*)d_in[1];
  const float* t_b  = (const float*)d_in[2];
  const float* t_ga = (const float*)d_in[3];
  const float* t_be = (const float*)d_in[4];
  const float* t_me = (const float*)d_in[5];
  const float* t_va = (const float*)d_in[6];
  const float* p_w  = (const float*)d_in[7];
  const float* p_b  = (const float*)d_in[8];
  const float* p_ga = (const float*)d_in[9];
  const float* p_be = (const float*)d_in[10];
  const float* p_me = (const float*)d_in[11];
  const float* p_va = (const float*)d_in[12];
  const float* g_w  = (const float*)d_in[13];
  const float* g_b  = (const float*)d_in[14];
  const float* g_ga = (const float*)d_in[15];
  const float* g_be = (const float*)d_in[16];
  const float* g_me = (const float*)d_in[17];
  const float* g_va = (const float*)d_in[18];
  const float* o_w  = (const float*)d_in[19];
  const float* o_b  = (const float*)d_in[20];
  const float* o_ga = (const float*)d_in[21];
  const float* o_be = (const float*)d_in[22];
  const float* o_me = (const float*)d_in[23];
  const float* o_va = (const float*)d_in[24];

  char* ws = (char*)d_ws;
  f16*    th    = (f16*)   (ws + OFF_THETA);
  f16*    ph    = (f16*)   (ws + OFF_PHI);
  f16*    gh    = (f16*)   (ws + OFF_G);
  f16*    gt    = (f16*)   (ws + OFF_GT);
  float2* pstat = (float2*)(ws + OFF_PSTAT);   // aliases gh (dead after k_tr_g)
  f16*    tpart = (f16*)   (ws + OFF_TPART);

  float* out0 = (float*)d_out;
  float* attn = out0 + (size_t)BB * CC * NN;

  k_prep<<<dim3(16, 16, BB), 256, 0, stream>>>(
      x, t_w, t_b, t_ga, t_be, t_me, t_va,
         p_w, p_b, p_ga, p_be, p_me, p_va,
         g_w, g_b, g_ga, g_be, g_me, g_va, th, ph, gh);
  k_tr_g<<<dim3(64, 2, BB), 256, 0, stream>>>(gh, gt);
  k_sweep1<<<1024, 256, 0, stream>>>(th, ph, pstat);
  k_sweep2<<<1024, 256, 0, stream>>>(th, ph, gt, pstat, attn, tpart);
  k_outconv<<<dim3(16, 4, BB), 256, 0, stream>>>(
      x, tpart, o_w, o_b, o_ga, o_be, o_me, o_va, out0);
}

// Round 9
// 558.636 us; speedup vs baseline: 1.3236x; 1.3236x over previous
//
#include <hip/hip_runtime.h>

// SelfAttention (non-local block), B=4, C=128, H=W=64, N=HW=4096.
// Outputs: [x + relu(bn(conv(attn@g)))] (2,097,152 f32)  ++  attn (67,108,864 f32)
//
// Layout fact: torch .view(B,-1,C) of a (B,C,H,W) buffer makes the (C,HW)
// conv output buffer literally the (N,C) row-major matrix (n*128+c == o*4096+s).
//
// Round-8 changes vs round-7 (739 us; sweep2 266 us: 16-rows/wave halved ILP
// and flush wrote 256B runs -> 1.37 TB/s write BW; occupancy unchanged 45.7%):
//  - sweep2 reverted to 32 rows/wave (round-4 geometry, sweep2 <168 us there),
//    keeping f16 P-LDS + fused stat merge.
//  - attn flush now writes 1KB-contiguous runs: P windowed at 256 cols; one
//    store instruction = one full row-run (64 lanes x 16B, f16->f32 from LDS).
//  - sweep1: 64 rows/wave (a[4][4], no acc) -> 4 MFMA per B-load, phi L2
//    traffic halved; 512-col chunks, grid 512.
// (Round 9 = re-run; round-8 bench hit a GPU-acquisition timeout, no data.)

typedef _Float16 f16;
typedef __attribute__((ext_vector_type(4))) _Float16 f16x4;
typedef __attribute__((ext_vector_type(8))) _Float16 f16x8;
typedef __attribute__((ext_vector_type(4))) float f32x4;

#define CC 128
#define NN 4096
#define BB 4
#define NC (NN * CC)
#define EPS_BN 1e-5f

// workspace offsets (bytes); total 32 MB
#define OFF_THETA (0ull)
#define OFF_PHI   (4ull << 20)
#define OFF_G     (8ull << 20)
#define OFF_GT    (12ull << 20)
#define OFF_PSTAT (8ull << 20)    // aliases G (dead after k_tr_g); [8][B][N] float2 = 1 MB
#define OFF_TPART (16ull << 20)   // [4][B][N][C] f16 = 16 MB

// ---------------------------------------------------------------------------
// K1: fused 1x1 conv + bias + relu + BN for theta/phi/g. 1 spatial/thread.
__global__ __launch_bounds__(256) void k_prep(
    const float* __restrict__ x,
    const float* __restrict__ t_w, const float* __restrict__ t_b,
    const float* __restrict__ t_ga, const float* __restrict__ t_be,
    const float* __restrict__ t_me, const float* __restrict__ t_va,
    const float* __restrict__ p_w, const float* __restrict__ p_b,
    const float* __restrict__ p_ga, const float* __restrict__ p_be,
    const float* __restrict__ p_me, const float* __restrict__ p_va,
    const float* __restrict__ g_w, const float* __restrict__ g_b,
    const float* __restrict__ g_ga, const float* __restrict__ g_be,
    const float* __restrict__ g_me, const float* __restrict__ g_va,
    f16* __restrict__ th, f16* __restrict__ ph, f16* __restrict__ gh)
{
  const int s  = blockIdx.x * 256 + threadIdx.x;
  const int o0 = blockIdx.y * 8;
  const int b  = blockIdx.z;
  const float* xb = x + (size_t)b * NC;

  float acc[3][8];
#pragma unroll
  for (int br = 0; br < 3; ++br)
#pragma unroll
    for (int j = 0; j < 8; ++j) acc[br][j] = 0.f;

#pragma unroll 4
  for (int c = 0; c < CC; ++c) {
    float xv = xb[c * NN + s];
#pragma unroll
    for (int j = 0; j < 8; ++j) {
      acc[0][j] += t_w[(o0 + j) * CC + c] * xv;   // uniform -> s_load
      acc[1][j] += p_w[(o0 + j) * CC + c] * xv;
      acc[2][j] += g_w[(o0 + j) * CC + c] * xv;
    }
  }

  f16* outs[3] = { th, ph, gh };
  const float* bi[3] = { t_b,  p_b,  g_b  };
  const float* ga[3] = { t_ga, p_ga, g_ga };
  const float* be[3] = { t_be, p_be, g_be };
  const float* me[3] = { t_me, p_me, g_me };
  const float* va[3] = { t_va, p_va, g_va };
#pragma unroll
  for (int br = 0; br < 3; ++br) {
#pragma unroll
    for (int j = 0; j < 8; ++j) {
      int o = o0 + j;
      float inv = ga[br][o] * rsqrtf(va[br][o] + EPS_BN);
      float add = be[br][o] - me[br][o] * inv;
      float y = fmaxf(acc[br][j] + bi[br][o], 0.f) * inv + add;
      outs[br][(size_t)b * NC + (size_t)o * NN + s] = (f16)y;
    }
  }
}

// ---------------------------------------------------------------------------
// K2: transpose g (N rows, C cols) -> gt (C rows, N cols), fp16.
__global__ __launch_bounds__(256) void k_tr_g(const f16* __restrict__ gh,
                                              f16* __restrict__ gt)
{
  __shared__ f16 tile[64][72];
  const int b   = blockIdx.z;
  const int m0  = blockIdx.x * 64;
  const int c20 = blockIdx.y * 64;
  const f16* gb_ = gh + (size_t)b * NC;
  f16* gtb = gt + (size_t)b * NC;
  const int t = threadIdx.x;
  {
    const int mr = t >> 2, co = (t & 3) * 16;
    f16x8 v0 = *(const f16x8*)(gb_ + (size_t)(m0 + mr) * CC + c20 + co);
    f16x8 v1 = *(const f16x8*)(gb_ + (size_t)(m0 + mr) * CC + c20 + co + 8);
#pragma unroll
    for (int j = 0; j < 8; ++j) tile[co + j][mr] = v0[j];
#pragma unroll
    for (int j = 0; j < 8; ++j) tile[co + 8 + j][mr] = v1[j];
  }
  __syncthreads();
  {
    const int cr = t >> 2, mo = (t & 3) * 16;
    f16x8 w0 = *(const f16x8*)(&tile[cr][mo]);
    f16x8 w1 = *(const f16x8*)(&tile[cr][mo + 8]);
    *(f16x8*)(gtb + (size_t)(c20 + cr) * NN + m0 + mo)     = w0;
    *(f16x8*)(gtb + (size_t)(c20 + cr) * NN + m0 + mo + 8) = w1;
  }
}

// ---------------------------------------------------------------------------
// MFMA 16x16x32 f16 maps: A: l -> A[l&15][(l>>4)*8+e]; B: l -> B[(l>>4)*8+e][l&15];
// D: l,r -> D[(l>>4)*4+r][l&15].
//
// K3 sweep1: stats only. 4 independent waves/block, 64 rows/wave, 512-col
// chunk. grid 512 = rb(16) x chunk(8) x b(4); b = bid&3 -> one batch per XCD.
__global__ __launch_bounds__(256, 2) void k_sweep1(
    const f16* __restrict__ th, const f16* __restrict__ ph_,
    float2* __restrict__ pstat)
{
  const int bid = blockIdx.x;
  const int b = bid & 3, chunk = (bid >> 2) & 7, rb = bid >> 5;
  const int tid = threadIdx.x, w = tid >> 6;
  const int lane = tid & 63, lr = lane & 15, lg = lane >> 4;
  const int n0w = rb * 256 + w * 64;
  const f16* tb_ = th  + (size_t)b * NC;
  const f16* pb_ = ph_ + (size_t)b * NC;

  f16x8 a[4][4];
#pragma unroll
  for (int tr = 0; tr < 4; ++tr)
#pragma unroll
    for (int kk = 0; kk < 4; ++kk)
      a[tr][kk] = *(const f16x8*)(tb_ + (size_t)(n0w + tr * 16 + lr) * CC + kk * 32 + lg * 8);

  float m[4][4], l[4][4];
#pragma unroll
  for (int tr = 0; tr < 4; ++tr)
#pragma unroll
    for (int r = 0; r < 4; ++r) { m[tr][r] = -1e30f; l[tr][r] = 0.f; }

  const int mbase = chunk * 512;
  for (int t = 0; t < 32; ++t) {
    const int mc = mbase + t * 16;
    f16x8 bf[4];
#pragma unroll
    for (int kk = 0; kk < 4; ++kk)
      bf[kk] = *(const f16x8*)(pb_ + (size_t)(mc + lr) * CC + kk * 32 + lg * 8);
#pragma unroll
    for (int tr = 0; tr < 4; ++tr) {
      f32x4 d = {0.f, 0.f, 0.f, 0.f};
#pragma unroll
      for (int kk = 0; kk < 4; ++kk)
        d = __builtin_amdgcn_mfma_f32_16x16x32_f16(a[tr][kk], bf[kk], d, 0, 0, 0);
#pragma unroll
      for (int r = 0; r < 4; ++r) {          // defer-max: 1 exp common path
        float dd = d[r] - m[tr][r];
        if (dd > 8.f) { l[tr][r] = l[tr][r] * __expf(-dd) + 1.f; m[tr][r] = d[r]; }
        else          { l[tr][r] += __expf(dd); }
      }
    }
  }
#pragma unroll
  for (int off = 1; off < 16; off <<= 1) {
#pragma unroll
    for (int tr = 0; tr < 4; ++tr)
#pragma unroll
      for (int r = 0; r < 4; ++r) {
        float mo = __shfl_xor(m[tr][r], off);
        float lo = __shfl_xor(l[tr][r], off);
        float mn = fmaxf(m[tr][r], mo);
        l[tr][r] = l[tr][r] * __expf(m[tr][r] - mn) + lo * __expf(mo - mn);
        m[tr][r] = mn;
      }
  }
  if (lr == 0) {
#pragma unroll
    for (int tr = 0; tr < 4; ++tr)
#pragma unroll
      for (int r = 0; r < 4; ++r)
        pstat[(size_t)(chunk * BB + b) * NN + n0w + tr * 16 + lg * 4 + r] =
            make_float2(m[tr][r], l[tr][r]);
  }
}

// ---------------------------------------------------------------------------
// K4 sweep2: 4 independent waves (no barriers), 32 rows/wave, 1024-col chunk,
// P windowed at 256 cols in LDS (f16), flush = 1KB-contiguous run per store.
// grid 512 = rb(32) x chunk(4) x b(4).
#define WSTR 264   // f16 row stride of 256-col P window (+8 pad)

__global__ __launch_bounds__(256, 2) void k_sweep2(
    const f16* __restrict__ th, const f16* __restrict__ ph_,
    const f16* __restrict__ gt, const float2* __restrict__ pstat,
    float* __restrict__ attn, f16* __restrict__ tpart)
{
  __shared__ f16 plds[4 * 32 * WSTR];               // 67.6 KB; per-wave private
  const int bid = blockIdx.x;
  const int b = bid & 3, chunk = (bid >> 2) & 3, rb = bid >> 4;
  const int tid = threadIdx.x, w = tid >> 6;
  const int lane = tid & 63, lr = lane & 15, lg = lane >> 4;
  const int n0w = rb * 128 + w * 32;
  const f16* tb_ = th  + (size_t)b * NC;
  const f16* pb_ = ph_ + (size_t)b * NC;
  const f16* gb_ = gt  + (size_t)b * NC;
  f16* pw = plds + w * 32 * WSTR;

  f16x8 aq[2][4];
#pragma unroll
  for (int tr = 0; tr < 2; ++tr)
#pragma unroll
    for (int kk = 0; kk < 4; ++kk)
      aq[tr][kk] = *(const f16x8*)(tb_ + (size_t)(n0w + tr * 16 + lr) * CC + kk * 32 + lg * 8);

  // inline stat merge over 8 col-chunks: S = M + ln(L) for this lane's rows
  float S[2][4];
#pragma unroll
  for (int tr = 0; tr < 2; ++tr)
#pragma unroll
    for (int r = 0; r < 4; ++r) {
      const int row = n0w + tr * 16 + lg * 4 + r;
      float mM = -1e30f, LL = 0.f;
#pragma unroll
      for (int ch = 0; ch < 8; ++ch) {
        float2 ps = pstat[(size_t)(ch * BB + b) * NN + row];
        float mn = fmaxf(mM, ps.x);
        LL = LL * __expf(mM - mn) + ps.y * __expf(ps.x - mn);
        mM = mn;
      }
      S[tr][r] = mM + __logf(LL);
    }

  f32x4 tacc[2][8];
#pragma unroll
  for (int tr = 0; tr < 2; ++tr)
#pragma unroll
    for (int ct = 0; ct < 8; ++ct) tacc[tr][ct] = (f32x4){0.f, 0.f, 0.f, 0.f};

  float* attn_b = attn + (size_t)b * NN * NN;
  const int mbase = chunk * 1024;

  for (int win = 0; win < 4; ++win) {               // 4 x 256-col windows
#pragma unroll
    for (int gi = 0; gi < 8; ++gi) {                // 8 x 32-col groups
      const int m0 = mbase + win * 256 + gi * 32;
      // ---- QK^T, P = exp(z - S) -> LDS (f16)
#pragma unroll
      for (int sub = 0; sub < 2; ++sub) {
        const int mc = m0 + sub * 16;
        f16x8 bf[4];
#pragma unroll
        for (int kk = 0; kk < 4; ++kk)
          bf[kk] = *(const f16x8*)(pb_ + (size_t)(mc + lr) * CC + kk * 32 + lg * 8);
#pragma unroll
        for (int tr = 0; tr < 2; ++tr) {
          f32x4 d = {0.f, 0.f, 0.f, 0.f};
#pragma unroll
          for (int kk = 0; kk < 4; ++kk)
            d = __builtin_amdgcn_mfma_f32_16x16x32_f16(aq[tr][kk], bf[kk], d, 0, 0, 0);
#pragma unroll
          for (int r = 0; r < 4; ++r)
            pw[(tr * 16 + lg * 4 + r) * WSTR + gi * 32 + sub * 16 + lr] =
                (f16)__expf(d[r] - S[tr][r]);
        }
      }
      // ---- PV A-fragment straight from this wave's LDS (in-order per wave)
      f16x8 pa[2];
#pragma unroll
      for (int tr = 0; tr < 2; ++tr)
        pa[tr] = *(const f16x8*)&pw[(tr * 16 + lr) * WSTR + gi * 32 + lg * 8];
      // ---- PV: tacc[tr][ct] += P(16x32) @ G(32x16c)
#pragma unroll
      for (int ct = 0; ct < 8; ++ct) {
        f16x8 gbf = *(const f16x8*)(gb_ + (size_t)(ct * 16 + lr) * NN + m0 + lg * 8);
#pragma unroll
        for (int tr = 0; tr < 2; ++tr)
          tacc[tr][ct] = __builtin_amdgcn_mfma_f32_16x16x32_f16(pa[tr], gbf, tacc[tr][ct], 0, 0, 0);
      }
    }
    // ---- flush window: one store instruction = one row's 1KB-contiguous run
    const int wcol = mbase + win * 256;
#pragma unroll 8
    for (int j = 0; j < 32; ++j) {
      f16x4 v = *(const f16x4*)&pw[j * WSTR + lane * 4];
      f32x4 o = { (float)v[0], (float)v[1], (float)v[2], (float)v[3] };
      __builtin_nontemporal_store(o,
          (f32x4*)(attn_b + (size_t)(n0w + j) * NN + wcol + lane * 4));
    }
    // WAR fence: flush reads must complete before next window's P writes
    asm volatile("s_waitcnt lgkmcnt(0)" ::: "memory");
  }

  // ---- tpart via LDS bounce -> contiguous coalesced f16 stores
#pragma unroll
  for (int tr = 0; tr < 2; ++tr)
#pragma unroll
    for (int ct = 0; ct < 8; ++ct)
#pragma unroll
      for (int r = 0; r < 4; ++r)
        pw[(tr * 16 + lg * 4 + r) * WSTR + ct * 16 + lr] = (f16)tacc[tr][ct][r];
  f16* tp = tpart + (size_t)(chunk * BB + b) * NC;
  const int frow = lane >> 4, fcol = (lane & 15) * 8;
#pragma unroll
  for (int j = 0; j < 8; ++j) {
    const int row = j * 4 + frow;
    f16x8 v = *(const f16x8*)&pw[row * WSTR + fcol];
    *(f16x8*)(tp + (size_t)(n0w + row) * CC + fcol) = v;
  }
}

// ---------------------------------------------------------------------------
// K5: out conv + BN + relu + residual, with tpart 4-chunk merge fused.
// t (N,C) flat == t_fm (C,HW) flat, so t_fm[b][c][hw] = tpart_flat[b][c*NN+hw].
__global__ __launch_bounds__(256) void k_outconv(
    const float* __restrict__ x, const f16* __restrict__ tpart,
    const float* __restrict__ o_w, const float* __restrict__ o_b,
    const float* __restrict__ o_ga, const float* __restrict__ o_be,
    const float* __restrict__ o_me, const float* __restrict__ o_va,
    float* __restrict__ out0)
{
  const int s  = blockIdx.x * 256 + threadIdx.x;
  const int o0 = blockIdx.y * 32;
  const int b  = blockIdx.z;
  const f16* tb_ = tpart + (size_t)b * NC;
  float acc[32];
#pragma unroll
  for (int j = 0; j < 32; ++j) acc[j] = 0.f;

#pragma unroll 2
  for (int c = 0; c < CC; ++c) {
    const size_t idx = (size_t)c * NN + s;
    float tv = (float)tb_[idx] +
               (float)tb_[(size_t)BB * NC + idx] +
               (float)tb_[(size_t)2 * BB * NC + idx] +
               (float)tb_[(size_t)3 * BB * NC + idx];
#pragma unroll
    for (int j = 0; j < 32; ++j)
      acc[j] += o_w[(o0 + j) * CC + c] * tv;        // uniform -> s_load
  }
#pragma unroll
  for (int j = 0; j < 32; ++j) {
    int o = o0 + j;
    float inv = o_ga[o] * rsqrtf(o_va[o] + EPS_BN);
    float add = o_be[o] - o_me[o] * inv;
    float y = fmaxf((acc[j] + o_b[o]) * inv + add, 0.f);
    size_t idx = (size_t)(b * CC + o) * NN + s;
    out0[idx] = x[idx] + y;
  }
}

// ---------------------------------------------------------------------------
extern "C" void kernel_launch(void* const* d_in, const int* in_sizes, int n_in,
                              void* d_out, int out_size, void* d_ws, size_t ws_size,
                              hipStream_t stream)
{
  (void)in_sizes; (void)n_in; (void)out_size; (void)ws_size;
  const float* x    = (const float*)d_in[0];
  const float* t_w  = (const float*)d_in[1];
  const float* t_b  = (const float*)d_in[2];
  const float* t_ga = (const float*)d_in[3];
  const float* t_be = (const float*)d_in[4];
  const float* t_me = (const float*)d_in[5];
  const float* t_va = (const float*)d_in[6];
  const float* p_w  = (const float*)d_in[7];
  const float* p_b  = (const float*)d_in[8];
  const float* p_ga = (const float*)d_in[9];
  const float* p_be = (const float*)d_in[10];
  const float* p_me = (const float*)d_in[11];
  const float* p_va = (const float*)d_in[12];
  const float* g_w  = (const float*)d_in[13];
  const float* g_b  = (const float*)d_in[14];
  const float* g_ga = (const float*)d_in[15];
  const float* g_be = (const float*)d_in[16];
  const float* g_me = (const float*)d_in[17];
  const float* g_va = (const float*)d_in[18];
  const float* o_w  = (const float*)d_in[19];
  const float* o_b  = (const float*)d_in[20];
  const float* o_ga = (const float*)d_in[21];
  const float* o_be = (const float*)d_in[22];
  const float* o_me = (const float*)d_in[23];
  const float* o_va = (const float*)d_in[24];

  char* ws = (char*)d_ws;
  f16*    th    = (f16*)   (ws + OFF_THETA);
  f16*    ph    = (f16*)   (ws + OFF_PHI);
  f16*    gh    = (f16*)   (ws + OFF_G);
  f16*    gt    = (f16*)   (ws + OFF_GT);
  float2* pstat = (float2*)(ws + OFF_PSTAT);   // aliases gh (dead after k_tr_g)
  f16*    tpart = (f16*)   (ws + OFF_TPART);

  float* out0 = (float*)d_out;
  float* attn = out0 + (size_t)BB * CC * NN;

  k_prep<<<dim3(16, 16, BB), 256, 0, stream>>>(
      x, t_w, t_b, t_ga, t_be, t_me, t_va,
         p_w, p_b, p_ga, p_be, p_me, p_va,
         g_w, g_b, g_ga, g_me == g_me ? g_be : g_be, g_me, g_va, th, ph, gh);
  k_tr_g<<<dim3(64, 2, BB), 256, 0, stream>>>(gh, gt);
  k_sweep1<<<512, 256, 0, stream>>>(th, ph, pstat);
  k_sweep2<<<512, 256, 0, stream>>>(th, ph, gt, pstat, attn, tpart);
  k_outconv<<<dim3(16, 4, BB), 256, 0, stream>>>(
      x, tpart, o_w, o_b, o_ga, o_be, o_me, o_va, out0);
}